// Round 1
// baseline (283.194 us; speedup 1.0000x reference)
//
#include <hip/hip_runtime.h>
#include <math.h>

#define E_DIM 4096
#define H_NUM 32
#define D_DIM 128
#define PAST_K 8191
#define K_TOT 8192

// workspace layout (float offsets)
#define WS_QUERY  0                         // 4096
#define WS_KV     4096                      // 256  (key_new[0:128], value_new[128:256])
#define WS_SCORES 8192                      // 32*8192 = 262144
#define WS_M      (8192 + 262144)           // 32
#define WS_L      (WS_M + 32)               // 32
#define WS_ATTN   (WS_L + 32)               // 4096

// ---------------------------------------------------------------- init
__global__ void k_init(float* __restrict__ ws, float* __restrict__ out) {
    int i = blockIdx.x * 256 + threadIdx.x;
    if (i < E_DIM) {
        ws[WS_QUERY + i] = 0.f;
        ws[WS_ATTN + i]  = 0.f;
        out[i] = 0.f;
    }
    if (i < 256) ws[WS_KV + i] = 0.f;
}

// ---------------------------------------------------------------- q + kv matvec (split-K, atomics)
// grid: (5, 64). bx<4 -> q outputs [bx*1024, +1024); bx==4 -> kv (256 outputs)
__global__ void k_qkv(const float* __restrict__ hs,
                      const float* __restrict__ q_w, const float* __restrict__ q_b,
                      const float* __restrict__ kv_w, const float* __restrict__ kv_b,
                      float* __restrict__ ws) {
    const int t = threadIdx.x;
    const int e0 = blockIdx.y * 64;
    const bool is_q = (blockIdx.x < 4);
    const float* W;
    const float* B;
    float* y;
    int nout, o;
    if (is_q) {
        W = q_w; B = q_b; y = ws + WS_QUERY; nout = E_DIM;
        o = blockIdx.x * 1024 + t * 4;
    } else {
        W = kv_w; B = kv_b; y = ws + WS_KV; nout = 256;
        if (t >= 64) return;
        o = t * 4;
    }
    float ax = 0.f, ay = 0.f, az = 0.f, aw = 0.f;
    for (int e = e0; e < e0 + 64; ++e) {
        const float x = hs[e];  // wave-uniform -> scalar load
        const float4 w = *reinterpret_cast<const float4*>(W + (size_t)e * nout + o);
        ax += x * w.x; ay += x * w.y; az += x * w.z; aw += x * w.w;
    }
    if (blockIdx.y == 0) {
        const float4 b = *reinterpret_cast<const float4*>(B + o);
        ax += b.x; ay += b.y; az += b.z; aw += b.w;
    }
    atomicAdd(&y[o + 0], ax);
    atomicAdd(&y[o + 1], ay);
    atomicAdd(&y[o + 2], az);
    atomicAdd(&y[o + 3], aw);
}

// ---------------------------------------------------------------- scores = q @ K / sqrt(D) + mask
// grid: (32, 4): 256 k per block.x, 8 heads per block.y
__global__ void k_scores(const float* __restrict__ past_key,
                         const float* __restrict__ mask,
                         float* __restrict__ ws,
                         float* __restrict__ out) {
    const int t = threadIdx.x;
    const int h0 = blockIdx.y * 8;
    const int k = blockIdx.x * 256 + t;
    const float* __restrict__ q = ws + WS_QUERY;
    const float* __restrict__ kvn = ws + WS_KV;

    float acc[8];
#pragma unroll
    for (int h = 0; h < 8; ++h) acc[h] = 0.f;

    for (int d = 0; d < D_DIM; ++d) {
        const float kval = (k < PAST_K) ? past_key[(size_t)d * PAST_K + k] : kvn[d];
#pragma unroll
        for (int h = 0; h < 8; ++h)
            acc[h] += q[(h0 + h) * D_DIM + d] * kval;  // q index wave-uniform -> s_load
    }
    const float scale = 0.08838834764831845f;  // 1/sqrt(128)
    const float mk = mask[k];
#pragma unroll
    for (int h = 0; h < 8; ++h)
        ws[WS_SCORES + (size_t)(h0 + h) * K_TOT + k] = acc[h] * scale + mk;

    // emit key_perm (out[4096:4224]) and value_new (out[4224:4352]) once
    if (blockIdx.x == 0 && blockIdx.y == 0 && t < 256) out[E_DIM + t] = kvn[t];
}

// ---------------------------------------------------------------- per-head softmax stats
// grid: 32 blocks (one head each), 256 threads
__global__ void k_stats(float* __restrict__ ws) {
    const int h = blockIdx.x;
    const int t = threadIdx.x;
    const float* __restrict__ s = ws + WS_SCORES + (size_t)h * K_TOT;
    __shared__ float red[256];

    float m = -3.4e38f;
    for (int k = t; k < K_TOT; k += 256) m = fmaxf(m, s[k]);
    red[t] = m;
    __syncthreads();
    for (int w = 128; w > 0; w >>= 1) {
        if (t < w) red[t] = fmaxf(red[t], red[t + w]);
        __syncthreads();
    }
    m = red[0];
    __syncthreads();

    float l = 0.f;
    for (int k = t; k < K_TOT; k += 256) l += __expf(s[k] - m);
    red[t] = l;
    __syncthreads();
    for (int w = 128; w > 0; w >>= 1) {
        if (t < w) red[t] += red[t + w];
        __syncthreads();
    }
    if (t == 0) {
        ws[WS_M + h] = m;
        ws[WS_L + h] = red[0];
    }
}

// ---------------------------------------------------------------- attn = softmax(scores) @ V (split-k, atomics)
// grid: (32, 4): 256 k per block.x, 8 heads per block.y; 256 threads = 128 d x 2 k-halves
__global__ void k_pv(const float* __restrict__ past_value, float* __restrict__ ws) {
    __shared__ float p[8][256];
    __shared__ float red[8][128];
    const int t = threadIdx.x;
    const int h0 = blockIdx.y * 8;
    const int k0 = blockIdx.x * 256;

    for (int i = t; i < 8 * 256; i += 256) {
        const int h = i >> 8, kl = i & 255;
        const float m = ws[WS_M + h0 + h];
        const float rl = 1.f / ws[WS_L + h0 + h];
        p[h][kl] = __expf(ws[WS_SCORES + (size_t)(h0 + h) * K_TOT + k0 + kl] - m) * rl;
    }
    __syncthreads();

    const int d = t & 127;
    const int half = t >> 7;
    float acc[8];
#pragma unroll
    for (int h = 0; h < 8; ++h) acc[h] = 0.f;

    for (int kl = half * 128; kl < half * 128 + 128; ++kl) {
        const int k = k0 + kl;
        const float v = (k < PAST_K) ? past_value[(size_t)k * D_DIM + d]
                                     : ws[WS_KV + 128 + d];
#pragma unroll
        for (int h = 0; h < 8; ++h) acc[h] += p[h][kl] * v;
    }

#pragma unroll
    for (int h = 0; h < 8; ++h)
        if (half == 1) red[h][d] = acc[h];
    __syncthreads();
    if (half == 0) {
#pragma unroll
        for (int h = 0; h < 8; ++h)
            atomicAdd(&ws[WS_ATTN + (h0 + h) * D_DIM + d], acc[h] + red[h][d]);
    }
}

// ---------------------------------------------------------------- out_proj matvec (split-K, atomics)
// grid: (4, 64)
__global__ void k_proj(const float* __restrict__ proj_w, const float* __restrict__ proj_b,
                       const float* __restrict__ ws, float* __restrict__ out) {
    const int t = threadIdx.x;
    const int o = blockIdx.x * 1024 + t * 4;
    const int e0 = blockIdx.y * 64;
    float ax = 0.f, ay = 0.f, az = 0.f, aw = 0.f;
    for (int e = e0; e < e0 + 64; ++e) {
        const float x = ws[WS_ATTN + e];  // wave-uniform -> scalar load
        const float4 w = *reinterpret_cast<const float4*>(proj_w + (size_t)e * E_DIM + o);
        ax += x * w.x; ay += x * w.y; az += x * w.z; aw += x * w.w;
    }
    if (blockIdx.y == 0) {
        const float4 b = *reinterpret_cast<const float4*>(proj_b + o);
        ax += b.x; ay += b.y; az += b.z; aw += b.w;
    }
    atomicAdd(&out[o + 0], ax);
    atomicAdd(&out[o + 1], ay);
    atomicAdd(&out[o + 2], az);
    atomicAdd(&out[o + 3], aw);
}

extern "C" void kernel_launch(void* const* d_in, const int* in_sizes, int n_in,
                              void* d_out, int out_size, void* d_ws, size_t ws_size,
                              hipStream_t stream) {
    const float* hs      = (const float*)d_in[0];
    const float* past_k  = (const float*)d_in[1];
    const float* past_v  = (const float*)d_in[2];
    const float* mask    = (const float*)d_in[3];
    const float* q_w     = (const float*)d_in[4];
    const float* q_b     = (const float*)d_in[5];
    const float* kv_w    = (const float*)d_in[6];
    const float* kv_b    = (const float*)d_in[7];
    const float* proj_w  = (const float*)d_in[8];
    const float* proj_b  = (const float*)d_in[9];
    float* out = (float*)d_out;
    float* ws  = (float*)d_ws;

    k_init<<<dim3(16), dim3(256), 0, stream>>>(ws, out);
    k_qkv<<<dim3(5, 64), dim3(256), 0, stream>>>(hs, q_w, q_b, kv_w, kv_b, ws);
    k_scores<<<dim3(32, 4), dim3(256), 0, stream>>>(past_k, mask, ws, out);
    k_stats<<<dim3(32), dim3(256), 0, stream>>>(ws);
    k_pv<<<dim3(32, 4), dim3(256), 0, stream>>>(past_v, ws);
    k_proj<<<dim3(4, 64), dim3(256), 0, stream>>>(proj_w, proj_b, ws, out);
}

// Round 2
// 227.179 us; speedup vs baseline: 1.2466x; 1.2466x over previous
//
#include <hip/hip_runtime.h>
#include <math.h>

#define E_DIM 4096
#define H_NUM 32
#define D_DIM 128
#define PAST_K 8191
#define K_TOT 8192

// workspace layout (float offsets)
#define WS_QUERY  0                          // 4096
#define WS_KV     4096                       // 256 (key_new 0:128, value_new 128:256)
#define WS_E      8192                       // 32*8192 unnormalized exp(scores)
#define WS_L      (WS_E + H_NUM * K_TOT)     // 32 (per-head sum of exps)
#define WS_ATTN   (WS_L + 64)                // 4096

// ---------------------------------------------------------------- init
__global__ void k_init(float* __restrict__ ws, float* __restrict__ out) {
    int i = blockIdx.x * 256 + threadIdx.x;
    if (i < E_DIM) {
        ws[WS_QUERY + i] = 0.f;
        ws[WS_ATTN + i]  = 0.f;
        out[i] = 0.f;
    }
    if (i < 256) ws[WS_KV + i] = 0.f;
    if (i < 32)  ws[WS_L + i] = 0.f;
}

// ---------------------------------------------------------------- q + kv matvec (split-K, atomics)
// grid: (5, 128). bx<4 -> q outputs [bx*1024,+1024); bx==4 -> kv (256 outputs). 32 e per by.
__global__ void k_qkv(const float* __restrict__ hs,
                      const float* __restrict__ q_w, const float* __restrict__ q_b,
                      const float* __restrict__ kv_w, const float* __restrict__ kv_b,
                      float* __restrict__ ws) {
    const int t = threadIdx.x;
    const int e0 = blockIdx.y * 32;
    if (blockIdx.x < 4) {
        const int o = blockIdx.x * 1024 + t * 4;
        float ax = 0.f, ay = 0.f, az = 0.f, aw = 0.f;
#pragma unroll
        for (int i = 0; i < 32; ++i) {
            const int e = e0 + i;
            const float x = hs[e];
            const float4 w = *reinterpret_cast<const float4*>(q_w + (size_t)e * E_DIM + o);
            ax += x * w.x; ay += x * w.y; az += x * w.z; aw += x * w.w;
        }
        if (blockIdx.y == 0) {
            const float4 b = *reinterpret_cast<const float4*>(q_b + o);
            ax += b.x; ay += b.y; az += b.z; aw += b.w;
        }
        float* y = ws + WS_QUERY + o;
        atomicAdd(y + 0, ax); atomicAdd(y + 1, ay);
        atomicAdd(y + 2, az); atomicAdd(y + 3, aw);
    } else {
        if (t >= 64) return;
        const int o = t * 4;
        float ax = 0.f, ay = 0.f, az = 0.f, aw = 0.f;
#pragma unroll
        for (int i = 0; i < 32; ++i) {
            const int e = e0 + i;
            const float x = hs[e];
            const float4 w = *reinterpret_cast<const float4*>(kv_w + (size_t)e * 256 + o);
            ax += x * w.x; ay += x * w.y; az += x * w.z; aw += x * w.w;
        }
        if (blockIdx.y == 0) {
            const float4 b = *reinterpret_cast<const float4*>(kv_b + o);
            ax += b.x; ay += b.y; az += b.z; aw += b.w;
        }
        float* y = ws + WS_KV + o;
        atomicAdd(y + 0, ax); atomicAdd(y + 1, ay);
        atomicAdd(y + 2, az); atomicAdd(y + 3, aw);
    }
}

// ---------------------------------------------------------------- exp(scores) + l, fused
// grid: (32, 4): 256 k per bx, 8 heads per by. 256 threads = 4 d-teams x 64 lanes.
// lane owns 4 consecutive k; team owns 32 d. Partials reduced via LDS; one wave
// does exp + per-head l wave-reduce + atomicAdd.
__global__ void k_scores(const float* __restrict__ past_key,
                         const float* __restrict__ mask,
                         float* __restrict__ ws,
                         float* __restrict__ out) {
    __shared__ float part[4 * 8 * 256];  // [team][h][k_local] = 32 KB
    const int t = threadIdx.x;
    const int lane = t & 63;
    const int team = t >> 6;
    const int d0 = __builtin_amdgcn_readfirstlane(team * 32);
    const int h0 = blockIdx.y * 8;
    const int k0 = blockIdx.x * 256;
    const int kq = k0 + lane * 4;
    const float* __restrict__ qb  = ws + WS_QUERY + h0 * D_DIM;
    const float* __restrict__ kvn = ws + WS_KV;

    float4 acc[8];
#pragma unroll
    for (int h = 0; h < 8; ++h) acc[h] = make_float4(0.f, 0.f, 0.f, 0.f);

    const bool tail = (kq + 3 >= PAST_K);  // loop-invariant; only kq+3 can hit k=8191
#pragma unroll 8
    for (int i = 0; i < 32; ++i) {
        const int d = d0 + i;
        const float* kp = past_key + (size_t)d * PAST_K + kq;
        const float* p3 = tail ? (kvn + d) : (kp + 3);  // branchless address select
        const float va = kp[0], vb = kp[1], vc = kp[2], vd = *p3;
#pragma unroll
        for (int h = 0; h < 8; ++h) {
            const float qv = qb[h * D_DIM + d];
            acc[h].x += qv * va; acc[h].y += qv * vb;
            acc[h].z += qv * vc; acc[h].w += qv * vd;
        }
    }
#pragma unroll
    for (int h = 0; h < 8; ++h)
        *reinterpret_cast<float4*>(&part[((team * 8 + h) * 64 + lane) * 4]) = acc[h];
    __syncthreads();

    if (t < 64) {
        const float scale = 0.08838834764831845f;  // 1/sqrt(128)
        const float4 mk = *reinterpret_cast<const float4*>(mask + kq);
#pragma unroll
        for (int h = 0; h < 8; ++h) {
            float4 s = *reinterpret_cast<float4*>(&part[((0 * 8 + h) * 64 + lane) * 4]);
#pragma unroll
            for (int tm = 1; tm < 4; ++tm) {
                const float4 r = *reinterpret_cast<float4*>(&part[((tm * 8 + h) * 64 + lane) * 4]);
                s.x += r.x; s.y += r.y; s.z += r.z; s.w += r.w;
            }
            float4 e;
            e.x = __expf(s.x * scale + mk.x);
            e.y = __expf(s.y * scale + mk.y);
            e.z = __expf(s.z * scale + mk.z);
            e.w = __expf(s.w * scale + mk.w);
            *reinterpret_cast<float4*>(ws + WS_E + (size_t)(h0 + h) * K_TOT + kq) = e;
            float lsum = e.x + e.y + e.z + e.w;
#pragma unroll
            for (int off = 32; off > 0; off >>= 1) lsum += __shfl_xor(lsum, off);
            if (lane == 0) atomicAdd(ws + WS_L + h0 + h, lsum);
        }
    }
    // emit key_perm (out[4096:4224]) and value_new (out[4224:4352]) once
    if (blockIdx.x == 0 && blockIdx.y == 0) out[E_DIM + t] = kvn[t];
}

// ---------------------------------------------------------------- attn = (e/l) @ V (split-k, atomics)
// grid: (32, 4): 256 k per bx, 8 heads per by. 256 threads = 8 k-groups x 32 d-quads.
__global__ void k_pv(const float* __restrict__ past_value, float* __restrict__ ws) {
    __shared__ float smem[8192];  // stage1: p[8][256] (first 8 KB); stage3: red[8g][8h][32dq]x4 (32 KB)
    const int t = threadIdx.x;
    const int h0 = blockIdx.y * 8;
    const int k0 = blockIdx.x * 256;

    // stage 1: normalized probabilities into LDS
#pragma unroll
    for (int i = 0; i < 8; ++i) {
        const float rl = 1.0f / ws[WS_L + h0 + i];
        smem[i * 256 + t] = ws[WS_E + (size_t)(h0 + i) * K_TOT + k0 + t] * rl;
    }
    __syncthreads();

    const int g  = t >> 5;
    const int dq = t & 31;
    const int d4 = dq * 4;
    const float* __restrict__ vnew = ws + WS_KV + D_DIM;

    float4 acc[8];
#pragma unroll
    for (int h = 0; h < 8; ++h) acc[h] = make_float4(0.f, 0.f, 0.f, 0.f);

#pragma unroll 8
    for (int kl = 0; kl < 32; ++kl) {
        const int k = k0 + g * 32 + kl;
        const float* vp = (k < PAST_K) ? (past_value + (size_t)k * D_DIM + d4)
                                       : (vnew + d4);  // branchless address select
        const float4 v = *reinterpret_cast<const float4*>(vp);
#pragma unroll
        for (int h = 0; h < 8; ++h) {
            const float p = smem[h * 256 + g * 32 + kl];
            acc[h].x += p * v.x; acc[h].y += p * v.y;
            acc[h].z += p * v.z; acc[h].w += p * v.w;
        }
    }
    __syncthreads();
#pragma unroll
    for (int h = 0; h < 8; ++h)
        *reinterpret_cast<float4*>(&smem[((g * 8 + h) * 32 + dq) * 4]) = acc[h];
    __syncthreads();

    // reduce over 8 k-groups: thread t -> (h = t>>5, dq = t&31)
    const int hh = t >> 5;
    float4 s = make_float4(0.f, 0.f, 0.f, 0.f);
#pragma unroll
    for (int gg = 0; gg < 8; ++gg) {
        const float4 r = *reinterpret_cast<float4*>(&smem[((gg * 8 + hh) * 32 + dq) * 4]);
        s.x += r.x; s.y += r.y; s.z += r.z; s.w += r.w;
    }
    float* a = ws + WS_ATTN + (h0 + hh) * D_DIM + d4;
    atomicAdd(a + 0, s.x); atomicAdd(a + 1, s.y);
    atomicAdd(a + 2, s.z); atomicAdd(a + 3, s.w);
}

// ---------------------------------------------------------------- out_proj matvec (split-K, atomics)
// grid: (4, 128)
__global__ void k_proj(const float* __restrict__ proj_w, const float* __restrict__ proj_b,
                       const float* __restrict__ ws, float* __restrict__ out) {
    const int t = threadIdx.x;
    const int o = blockIdx.x * 1024 + t * 4;
    const int e0 = blockIdx.y * 32;
    float ax = 0.f, ay = 0.f, az = 0.f, aw = 0.f;
#pragma unroll
    for (int i = 0; i < 32; ++i) {
        const int e = e0 + i;
        const float x = ws[WS_ATTN + e];  // wave-uniform -> scalar load
        const float4 w = *reinterpret_cast<const float4*>(proj_w + (size_t)e * E_DIM + o);
        ax += x * w.x; ay += x * w.y; az += x * w.z; aw += x * w.w;
    }
    if (blockIdx.y == 0) {
        const float4 b = *reinterpret_cast<const float4*>(proj_b + o);
        ax += b.x; ay += b.y; az += b.z; aw += b.w;
    }
    atomicAdd(out + o + 0, ax); atomicAdd(out + o + 1, ay);
    atomicAdd(out + o + 2, az); atomicAdd(out + o + 3, aw);
}

extern "C" void kernel_launch(void* const* d_in, const int* in_sizes, int n_in,
                              void* d_out, int out_size, void* d_ws, size_t ws_size,
                              hipStream_t stream) {
    const float* hs      = (const float*)d_in[0];
    const float* past_k  = (const float*)d_in[1];
    const float* past_v  = (const float*)d_in[2];
    const float* mask    = (const float*)d_in[3];
    const float* q_w     = (const float*)d_in[4];
    const float* q_b     = (const float*)d_in[5];
    const float* kv_w    = (const float*)d_in[6];
    const float* kv_b    = (const float*)d_in[7];
    const float* proj_w  = (const float*)d_in[8];
    const float* proj_b  = (const float*)d_in[9];
    float* out = (float*)d_out;
    float* ws  = (float*)d_ws;

    k_init  <<<dim3(16),     dim3(256), 0, stream>>>(ws, out);
    k_qkv   <<<dim3(5, 128), dim3(256), 0, stream>>>(hs, q_w, q_b, kv_w, kv_b, ws);
    k_scores<<<dim3(32, 4),  dim3(256), 0, stream>>>(past_k, mask, ws, out);
    k_pv    <<<dim3(32, 4),  dim3(256), 0, stream>>>(past_v, ws);
    k_proj  <<<dim3(4, 128), dim3(256), 0, stream>>>(proj_w, proj_b, ws, out);
}